// Round 3
// baseline (94.622 us; speedup 1.0000x reference)
//
#include <hip/hip_runtime.h>

// BahdanauAttention: B=4, LQ=512, LK=512, H=256, all f32.
//   q = query@Wq^T+bq ; k = values@Wk^T+bk
//   scores = sum_h We[h]*tanh(q+k) + be -> softmax over k -> context = attn@values
//
// Algebra:
//   tanh(x) = 1 - 2/(exp(2x)+1); be and sum(We) are additive constants on scores
//   -> softmax-invariant -> dropped. softmax(scores) = softmax(-2t) with
//   t = sum_h We_h/(1+Eq_h*Ek_h), Eq=exp2(SCALE2*q), Ek=exp2(SCALE2*k) precomputed
//   in the projection epilogue (Ek stored transposed [b][h][k]).
//   Quad-rcp: for 4 k-elements, x_i = 1+Eq*Ek_i, P=x0x1x2x3, r=rcp(P);
//   1/x_i = r * (product of other three) via prefix products p01,p23 ->
//   14 VALU + 1 trans per 4 elements (one rcp amortized over 4).
//   Overflow-safe: P = e^{sum 2(q+k)} <= ~e^48 << 3.4e38; all x_i >= 1.
// Timing note: the timed graph includes a harness-side 256MiB d_ws poison fill
// (~40us @ 6.8TB/s) that we cannot remove; addressable kernel budget ~41us.

#define SCALE2 2.8853900817779268f   // 2*log2(e)

#if defined(__has_builtin)
#if __has_builtin(__builtin_amdgcn_exp2f)
#define FEXP2(x) __builtin_amdgcn_exp2f(x)
#endif
#if __has_builtin(__builtin_amdgcn_rcpf)
#define FRCP(x) __builtin_amdgcn_rcpf(x)
#endif
#endif
#ifndef FEXP2
#define FEXP2(x) exp2f(x)
#endif
#ifndef FRCP
#define FRCP(x) (1.0f/(x))
#endif

// Fused projections. blockIdx.z = 0: Eq[n][o] = exp2(SCALE2*(query@Wq^T+bq))
//                    blockIdx.z = 1: EkT[b][o][k] = exp2(SCALE2*(values@Wk^T+bk))
__global__ __launch_bounds__(512) void proj_kernel(
    const float* __restrict__ Q, const float* __restrict__ V,
    const float* __restrict__ Wq, const float* __restrict__ bq,
    const float* __restrict__ Wk, const float* __restrict__ bk,
    float* __restrict__ Eq, float* __restrict__ EkT)
{
  const int n0 = blockIdx.x * 64;
  const int o0 = blockIdx.y * 64;
  const bool isK = (blockIdx.z == 1);
  const float* X    = isK ? V  : Q;
  const float* W    = isK ? Wk : Wq;
  const float* bias = isK ? bk : bq;
  const int t  = threadIdx.x;
  const int tx = t & 15;        // o quad
  const int ty = t >> 4;        // 0..31 : n pair
  __shared__ float Xst[32][68]; // [h][n]
  __shared__ float Wst[32][68]; // [h][o]
  float acc[2][4] = {};
  for (int h0 = 0; h0 < 256; h0 += 32) {
    __syncthreads();
    {
      int r = t >> 3, c = (t & 7) << 2;   // 64 rows x 32 cols
      float4 xv = *(const float4*)(X + (size_t)(n0 + r) * 256 + h0 + c);
      Xst[c  ][r] = xv.x; Xst[c+1][r] = xv.y; Xst[c+2][r] = xv.z; Xst[c+3][r] = xv.w;
      float4 wv = *(const float4*)(W + (size_t)(o0 + r) * 256 + h0 + c);
      Wst[c  ][r] = wv.x; Wst[c+1][r] = wv.y; Wst[c+2][r] = wv.z; Wst[c+3][r] = wv.w;
    }
    __syncthreads();
#pragma unroll 8
    for (int hh = 0; hh < 32; ++hh) {
      float2 a  = *(const float2*)&Xst[hh][ty*2];
      float4 bb = *(const float4*)&Wst[hh][tx*4];
      acc[0][0] = fmaf(a.x, bb.x, acc[0][0]); acc[0][1] = fmaf(a.x, bb.y, acc[0][1]);
      acc[0][2] = fmaf(a.x, bb.z, acc[0][2]); acc[0][3] = fmaf(a.x, bb.w, acc[0][3]);
      acc[1][0] = fmaf(a.y, bb.x, acc[1][0]); acc[1][1] = fmaf(a.y, bb.y, acc[1][1]);
      acc[1][2] = fmaf(a.y, bb.z, acc[1][2]); acc[1][3] = fmaf(a.y, bb.w, acc[1][3]);
    }
  }
  const float4 bv = *(const float4*)(bias + o0 + tx*4);
  float e[2][4];
#pragma unroll
  for (int i = 0; i < 2; ++i) {
    e[i][0] = FEXP2(SCALE2 * (acc[i][0] + bv.x));
    e[i][1] = FEXP2(SCALE2 * (acc[i][1] + bv.y));
    e[i][2] = FEXP2(SCALE2 * (acc[i][2] + bv.z));
    e[i][3] = FEXP2(SCALE2 * (acc[i][3] + bv.w));
  }
  if (!isK) {
#pragma unroll
    for (int i = 0; i < 2; ++i) {
      float4 st = {e[i][0], e[i][1], e[i][2], e[i][3]};
      *(float4*)(Eq + (size_t)(n0 + ty*2 + i) * 256 + o0 + tx*4) = st;
    }
  } else {
    const int b  = n0 >> 9;
    const int k0 = (n0 & 511) + ty*2;
#pragma unroll
    for (int j = 0; j < 4; ++j) {
      float2 st = {e[0][j], e[1][j]};
      *(float2*)(EkT + (size_t)b*131072 + (size_t)(o0 + tx*4 + j)*512 + k0) = st;
    }
  }
}

// Fused scores + softmax + context. 4 q-rows/block, 512 blocks, 512 threads.
// Each thread owns 4 k-columns of one q-row through the whole scores phase.
__global__ __launch_bounds__(512) void fused_kernel(
    const float* __restrict__ Eq, const float* __restrict__ EkT,
    const float* __restrict__ We, const float* __restrict__ values,
    float* __restrict__ attn, float* __restrict__ ctx)
{
  const int t    = threadIdx.x;
  const int blk  = blockIdx.x;          // 0..511
  const int b    = blk >> 7;            // 128 blocks per batch
  const int q0   = (blk & 127) * 4;
  const int row0 = b * 512 + q0;

  __shared__ float smem[16 * 512];      // 32KB: ks (scores) then vs (ctx)
  float (*ks)[512] = (float (*)[512])smem;   // [16 h][512 k]
  float (*vs)[256] = (float (*)[256])smem;   // [32 k][256 h]
  __shared__ float qs[4][256];          // 4KB  Eq rows
  __shared__ float ts[4][512];          // 8KB  raw t -> normalized attn

  // stage Eq rows once (read BEFORE ctx overwrites this region at the end)
  if (t < 256) {
    int r = t >> 6, c = (t & 63) << 2;
    *(float4*)&qs[r][c] = *(const float4*)(Eq + (size_t)(row0 + r) * 256 + c);
  }

  const int qi = t >> 7;                // 0..3  q-row
  const int k4 = (t & 127) << 2;        // 0..508 k quad
  const float* ekb = EkT + (size_t)b * 131072;

  float a0 = 0.f, a1 = 0.f, a2 = 0.f, a3 = 0.f;
  for (int h0 = 0; h0 < 256; h0 += 16) {
    __syncthreads();
#pragma unroll
    for (int rep = 0; rep < 4; ++rep) {  // stage ks[16][512], b128 contiguous
      int idx = rep * 512 + t;
      int r = idx >> 7, c = (idx & 127) << 2;
      *(float4*)&ks[r][c] = *(const float4*)(ekb + (size_t)(h0 + r) * 512 + c);
    }
    __syncthreads();
#pragma unroll
    for (int hh = 0; hh < 16; ++hh) {
      float w  = We[h0 + hh];                      // wave-uniform -> s_load
      float qv = qs[qi][h0 + hh];                  // wave-uniform broadcast
      float4 kv = *(const float4*)&ks[hh][k4];     // b128 lane-consecutive
      float x0 = fmaf(qv, kv.x, 1.0f);
      float x1 = fmaf(qv, kv.y, 1.0f);
      float x2 = fmaf(qv, kv.z, 1.0f);
      float x3 = fmaf(qv, kv.w, 1.0f);
      float p01 = x0 * x1, p23 = x2 * x3;
      float r4  = FRCP(p01 * p23);                 // one rcp per 4 elements
      float wr  = w * r4;
      float sw  = wr * p23, uw = wr * p01;
      a0 = fmaf(sw, x1, a0);
      a1 = fmaf(sw, x0, a1);
      a2 = fmaf(uw, x3, a2);
      a3 = fmaf(uw, x2, a3);
    }
  }
  {
    float4 st = {a0, a1, a2, a3};
    *(float4*)&ts[qi][k4] = st;
  }
  __syncthreads();

  // softmax(-2t) per row: waves 0..3 own one row each; exponent (mn-t)*SCALE2
  {
    const int wid = t >> 6, j = t & 63;
    if (wid < 4) {
      float v[8];
      float mn = 1e30f;
#pragma unroll
      for (int i = 0; i < 8; ++i) { v[i] = ts[wid][j + 64*i]; mn = fminf(mn, v[i]); }
#pragma unroll
      for (int off = 32; off > 0; off >>= 1) mn = fminf(mn, __shfl_xor(mn, off, 64));
      float sum = 0.f;
#pragma unroll
      for (int i = 0; i < 8; ++i) { v[i] = FEXP2((mn - v[i]) * SCALE2); sum += v[i]; }
#pragma unroll
      for (int off = 32; off > 0; off >>= 1) sum += __shfl_xor(sum, off, 64);
      float inv = 1.0f / sum;
      float* gp = attn + (size_t)(row0 + wid) * 512 + j;
#pragma unroll
      for (int i = 0; i < 8; ++i) {
        float p = v[i] * inv;
        ts[wid][j + 64*i] = p;
        gp[64*i] = p;                   // coalesced b32 stores
      }
    }
  }

  // context: thread -> (row r2, 2 h-cols); vs aliases dead ks buffer
  const int r2 = t >> 7;
  const int h2 = (t & 127) << 1;
  float c0 = 0.f, c1 = 0.f;
  const float* vb = values + (size_t)b * 131072;
  for (int kc = 0; kc < 512; kc += 32) {
    __syncthreads();                    // also orders softmax ts writes (kc=0)
#pragma unroll
    for (int rep = 0; rep < 4; ++rep) { // stage vs[32][256]
      int idx = rep * 512 + t;
      int r = idx >> 6, c = (idx & 63) << 2;
      *(float4*)&vs[r][c] = *(const float4*)(vb + (size_t)(kc + r) * 256 + c);
    }
    __syncthreads();
#pragma unroll
    for (int kk = 0; kk < 32; ++kk) {
      float av = ts[r2][kc + kk];                 // wave-uniform broadcast
      float2 vv = *(const float2*)&vs[kk][h2];    // lane-consecutive b64
      c0 = fmaf(av, vv.x, c0);
      c1 = fmaf(av, vv.y, c1);
    }
  }
  float2 st = {c0, c1};
  *(float2*)(ctx + (size_t)(row0 + r2) * 256 + h2) = st;
}

extern "C" void kernel_launch(void* const* d_in, const int* in_sizes, int n_in,
                              void* d_out, int out_size, void* d_ws, size_t ws_size,
                              hipStream_t stream)
{
  const float* query  = (const float*)d_in[0];
  const float* values = (const float*)d_in[1];
  const float* Wq     = (const float*)d_in[2];
  const float* bq     = (const float*)d_in[3];
  const float* Wk     = (const float*)d_in[4];
  const float* bk     = (const float*)d_in[5];
  const float* We     = (const float*)d_in[6];
  // d_in[7] = be: additive constant on scores -> softmax-invariant -> unused.

  float* ctx  = (float*)d_out;            // 4*512*256 floats
  float* attn = ctx + 4*512*256;          // 4*512*512 floats
  float* Eq   = ctx;                      // alias ctx region; each fused block
                                          // reads only its own 4 Eq rows before
                                          // writing those same ctx rows
  float* EkT  = (float*)d_ws;             // 2MB of ws, layout [b][h][k]

  proj_kernel <<<dim3(32, 4, 2), 512, 0, stream>>>(query, values, Wq, bq, Wk, bk, Eq, EkT);
  fused_kernel<<<512, 512, 0, stream>>>(Eq, EkT, We, values, attn, ctx);
}

// Round 4
// 79.191 us; speedup vs baseline: 1.1949x; 1.1949x over previous
//
#include <hip/hip_runtime.h>

// BahdanauAttention: B=4, LQ=512, LK=512, H=256, all f32.
//   q = query@Wq^T+bq ; k = values@Wk^T+bk
//   scores = sum_h We[h]*tanh(q+k) + be -> softmax over k -> context = attn@values
//
// Algebra:
//   tanh(x) = 1 - 2/(exp(2x)+1); be and sum(We) are additive constants on scores
//   -> softmax-invariant -> dropped. softmax(scores) = softmax(-2t) with
//   t = sum_h We_h/(1+Eq_h*Ek_h), Eq=exp2(SCALE2*q), Ek=exp2(SCALE2*k) precomputed
//   in the projection epilogue (Ek stored transposed [b][h][k]).
//   Pair-rcp: x0=1+Eq*Ek0, x1=1+Eq*Ek1, r=rcp(x0*x1); 1/x0=r*x1, 1/x1=r*x0 ->
//   6 VALU + 1 trans per 2 elements (trans pressure halved vs 1 rcp/element).
//   Overflow-safe: x0*x1 <= ~e^48 << 3.4e38; x_i >= 1, no cancellation.
//
// Structure: round-2 split kernels (fused variant regressed: 2 blocks/CU,
// 3.5x L2 re-staging, 41% VALUBusy). Round-2 geometry restored verbatim;
// only the scores inner loop changes.

#define SCALE2 2.8853900817779268f   // 2*log2(e)

#if defined(__has_builtin)
#if __has_builtin(__builtin_amdgcn_exp2f)
#define FEXP2(x) __builtin_amdgcn_exp2f(x)
#endif
#if __has_builtin(__builtin_amdgcn_rcpf)
#define FRCP(x) __builtin_amdgcn_rcpf(x)
#endif
#endif
#ifndef FEXP2
#define FEXP2(x) exp2f(x)
#endif
#ifndef FRCP
#define FRCP(x) (1.0f/(x))
#endif

// Fused projections. blockIdx.z = 0: Eq[n][o] = exp2(SCALE2*(query@Wq^T+bq))
//                    blockIdx.z = 1: EkT[b][o][k] = exp2(SCALE2*(values@Wk^T+bk))
__global__ __launch_bounds__(512) void proj_kernel(
    const float* __restrict__ Q, const float* __restrict__ V,
    const float* __restrict__ Wq, const float* __restrict__ bq,
    const float* __restrict__ Wk, const float* __restrict__ bk,
    float* __restrict__ Eq, float* __restrict__ EkT)
{
  const int n0 = blockIdx.x * 64;
  const int o0 = blockIdx.y * 64;
  const bool isK = (blockIdx.z == 1);
  const float* X    = isK ? V  : Q;
  const float* W    = isK ? Wk : Wq;
  const float* bias = isK ? bk : bq;
  const int t  = threadIdx.x;
  const int tx = t & 15;        // o quad
  const int ty = t >> 4;        // 0..31 : n pair
  __shared__ float Xst[32][68]; // [h][n]
  __shared__ float Wst[32][68]; // [h][o]
  float acc[2][4] = {};
  for (int h0 = 0; h0 < 256; h0 += 32) {
    __syncthreads();
    {
      int r = t >> 3, c = (t & 7) << 2;   // 64 rows x 32 cols
      float4 xv = *(const float4*)(X + (size_t)(n0 + r) * 256 + h0 + c);
      Xst[c  ][r] = xv.x; Xst[c+1][r] = xv.y; Xst[c+2][r] = xv.z; Xst[c+3][r] = xv.w;
      float4 wv = *(const float4*)(W + (size_t)(o0 + r) * 256 + h0 + c);
      Wst[c  ][r] = wv.x; Wst[c+1][r] = wv.y; Wst[c+2][r] = wv.z; Wst[c+3][r] = wv.w;
    }
    __syncthreads();
#pragma unroll 8
    for (int hh = 0; hh < 32; ++hh) {
      float2 a  = *(const float2*)&Xst[hh][ty*2];
      float4 bb = *(const float4*)&Wst[hh][tx*4];
      acc[0][0] = fmaf(a.x, bb.x, acc[0][0]); acc[0][1] = fmaf(a.x, bb.y, acc[0][1]);
      acc[0][2] = fmaf(a.x, bb.z, acc[0][2]); acc[0][3] = fmaf(a.x, bb.w, acc[0][3]);
      acc[1][0] = fmaf(a.y, bb.x, acc[1][0]); acc[1][1] = fmaf(a.y, bb.y, acc[1][1]);
      acc[1][2] = fmaf(a.y, bb.z, acc[1][2]); acc[1][3] = fmaf(a.y, bb.w, acc[1][3]);
    }
  }
  const float4 bv = *(const float4*)(bias + o0 + tx*4);
  float e[2][4];
#pragma unroll
  for (int i = 0; i < 2; ++i) {
    e[i][0] = FEXP2(SCALE2 * (acc[i][0] + bv.x));
    e[i][1] = FEXP2(SCALE2 * (acc[i][1] + bv.y));
    e[i][2] = FEXP2(SCALE2 * (acc[i][2] + bv.z));
    e[i][3] = FEXP2(SCALE2 * (acc[i][3] + bv.w));
  }
  if (!isK) {
#pragma unroll
    for (int i = 0; i < 2; ++i) {
      float4 st = {e[i][0], e[i][1], e[i][2], e[i][3]};
      *(float4*)(Eq + (size_t)(n0 + ty*2 + i) * 256 + o0 + tx*4) = st;
    }
  } else {
    const int b  = n0 >> 9;
    const int k0 = (n0 & 511) + ty*2;
#pragma unroll
    for (int j = 0; j < 4; ++j) {
      float2 st = {e[0][j], e[1][j]};
      *(float2*)(EkT + (size_t)b*131072 + (size_t)(o0 + tx*4 + j)*512 + k0) = st;
    }
  }
}

// traw[b][q][k] = sum_h We[h] * rcp(Eq*Ek + 1)   (scores = C - 2*traw)
// tile 8q x 64k, 256 threads, 2 el/thread. grid (8,64,4) = 2048 blocks,
// LDS ~18.5KB -> ~8 blocks/CU.
__global__ __launch_bounds__(256) void scores_kernel(
    const float* __restrict__ Eq, const float* __restrict__ EkT,
    const float* __restrict__ We, float* __restrict__ sout)
{
  const int kt = blockIdx.x;      // 0..7
  const int qt = blockIdx.y;      // 0..63
  const int b  = blockIdx.z;      // 0..3
  const int t  = threadIdx.x;
  const int qi = t >> 5;          // 0..7
  const int k2 = (t & 31) << 1;   // 0..62

  __shared__ float ks[64][64];    // [h][k] — staged straight from EkT
  __shared__ float qs[8][68];

  const float* eqbase = Eq  + (size_t)(b*512 + qt*8) * 256;
  const float* ekbase = EkT + (size_t)b*131072 + (size_t)kt*64;

  float acc0 = 0.f, acc1 = 0.f;

  for (int h0 = 0; h0 < 256; h0 += 64) {
    __syncthreads();
    if (t < 128) {                 // stage q tile 8x64
      int r = t >> 4, c = (t & 15) << 2;
      float4 v = *(const float4*)(eqbase + (size_t)r*256 + h0 + c);
      qs[r][c] = v.x; qs[r][c+1] = v.y; qs[r][c+2] = v.z; qs[r][c+3] = v.w;
    }
#pragma unroll
    for (int rep = 0; rep < 4; ++rep) {  // stage k tile 64h x 64k, b128 writes
      int idx = rep*256 + t;
      int r = idx >> 4, c = (idx & 15) << 2;
      *(float4*)&ks[r][c] = *(const float4*)(ekbase + (size_t)(h0 + r)*512 + c);
    }
    __syncthreads();
#pragma unroll 8
    for (int hh = 0; hh < 64; ++hh) {
      float w  = We[h0 + hh];                      // uniform -> s_load
      float qv = qs[qi][hh];                       // broadcast
      float2 kv = *(const float2*)&ks[hh][k2];     // b64, 2-way = free
      float x0 = fmaf(qv, kv.x, 1.0f);
      float x1 = fmaf(qv, kv.y, 1.0f);
      float r2 = FRCP(x0 * x1);                    // one rcp per 2 elements
      float wr = w * r2;
      acc0 = fmaf(wr, x1, acc0);                   // w/x0
      acc1 = fmaf(wr, x0, acc1);                   // w/x1
    }
  }
  float2 st = {acc0, acc1};
  *(float2*)(sout + (size_t)(b*512 + qt*8 + qi)*512 + kt*64 + k2) = st;
}

// Fused softmax + context. 8 rows/block, 256 blocks.
// Reads raw t from attn buffer, writes normalized attn (softmax(-2t)) in place
// and ctx[row][h] = sum_k attn[row][k]*values[b][k][h].
__global__ __launch_bounds__(256) void ctx_kernel(
    const float* __restrict__ values, float* attn, float* __restrict__ ctx)
{
  const int t    = threadIdx.x;
  const int row0 = blockIdx.x * 8;
  const int b    = row0 >> 9;
  __shared__ float ts[8][512];
  __shared__ float vs[32][256];
#pragma unroll
  for (int rep = 0; rep < 4; ++rep) {     // stage raw scores 8x512
    int idx = rep*256 + t;
    int r = idx >> 7, c = (idx & 127) << 2;
    *(float4*)&ts[r][c] = *(const float4*)(attn + (size_t)(row0 + r)*512 + c);
  }
  __syncthreads();
  {  // softmax: 32 threads per row; exponent (mn - v)*SCALE2 since scores = C-2t
    const int row = t >> 5, j = t & 31;
    float v[16];
    float mn = 1e30f;
#pragma unroll
    for (int i = 0; i < 16; ++i) { v[i] = ts[row][j + 32*i]; mn = fminf(mn, v[i]); }
#pragma unroll
    for (int off = 16; off > 0; off >>= 1) mn = fminf(mn, __shfl_xor(mn, off, 32));
    float sum = 0.f;
#pragma unroll
    for (int i = 0; i < 16; ++i) { v[i] = FEXP2((mn - v[i]) * SCALE2); sum += v[i]; }
#pragma unroll
    for (int off = 16; off > 0; off >>= 1) sum += __shfl_xor(sum, off, 32);
    const float inv = 1.0f / sum;
    float* gp = attn + (size_t)(row0 + row)*512 + j;
#pragma unroll
    for (int i = 0; i < 16; ++i) {
      float p = v[i] * inv;
      ts[row][j + 32*i] = p;
      gp[32*i] = p;
    }
  }
  // context
  const int h4 = (t & 63) << 2;
  const int r0 = (t >> 6) * 2;            // wave-uniform
  float4 acc0 = {0,0,0,0}, acc1 = {0,0,0,0};
  const float* vbase = values + (size_t)b * 512 * 256;
  for (int kc = 0; kc < 512; kc += 32) {
    __syncthreads();
#pragma unroll
    for (int rep = 0; rep < 8; ++rep) {   // stage values 32x256
      int idx = rep*256 + t;
      int r = idx >> 6, c = (idx & 63) << 2;
      *(float4*)&vs[r][c] = *(const float4*)(vbase + (size_t)(kc + r)*256 + c);
    }
    __syncthreads();
#pragma unroll 8
    for (int kk = 0; kk < 32; ++kk) {
      float4 v = *(const float4*)&vs[kk][h4];   // lanes consecutive, conflict-free
      float a0 = ts[r0  ][kc+kk];               // wave-uniform broadcast
      float a1 = ts[r0+1][kc+kk];
      acc0.x = fmaf(a0, v.x, acc0.x); acc0.y = fmaf(a0, v.y, acc0.y);
      acc0.z = fmaf(a0, v.z, acc0.z); acc0.w = fmaf(a0, v.w, acc0.w);
      acc1.x = fmaf(a1, v.x, acc1.x); acc1.y = fmaf(a1, v.y, acc1.y);
      acc1.z = fmaf(a1, v.z, acc1.z); acc1.w = fmaf(a1, v.w, acc1.w);
    }
  }
  *(float4*)(ctx + (size_t)(row0 + r0    )*256 + h4) = acc0;
  *(float4*)(ctx + (size_t)(row0 + r0 + 1)*256 + h4) = acc1;
}

extern "C" void kernel_launch(void* const* d_in, const int* in_sizes, int n_in,
                              void* d_out, int out_size, void* d_ws, size_t ws_size,
                              hipStream_t stream)
{
  const float* query  = (const float*)d_in[0];
  const float* values = (const float*)d_in[1];
  const float* Wq     = (const float*)d_in[2];
  const float* bq     = (const float*)d_in[3];
  const float* Wk     = (const float*)d_in[4];
  const float* bk     = (const float*)d_in[5];
  const float* We     = (const float*)d_in[6];
  // d_in[7] = be: additive constant on scores -> softmax-invariant -> unused.

  float* ctx  = (float*)d_out;            // 4*512*256 floats
  float* attn = ctx + 4*512*256;          // 4*512*512 floats
  float* Eq   = ctx;                      // alias ctx region; all Eq reads happen
                                          // in scores_kernel, before ctx_kernel
  float* EkT  = (float*)d_ws;             // 2MB of ws, layout [b][h][k]

  proj_kernel  <<<dim3(32, 4, 2), 512, 0, stream>>>(query, values, Wq, bq, Wk, bk, Eq, EkT);
  scores_kernel<<<dim3(8, 64, 4), 256, 0, stream>>>(Eq, EkT, We, attn);
  ctx_kernel   <<<256, 256, 0, stream>>>(values, attn, ctx);
}